// Round 4
// baseline (141.399 us; speedup 1.0000x reference)
//
#include <hip/hip_runtime.h>
#include <hip/hip_bf16.h>

typedef __attribute__((ext_vector_type(8)))  short  short8;
typedef __attribute__((ext_vector_type(4)))  float  f32x4;
typedef __attribute__((ext_vector_type(16))) float  f32x16;

#define DEVINL static __device__ __forceinline__

constexpr int BATCH = 8;
constexpr int SEQ   = 4096;
constexpr int EMB   = 256;
constexpr int HD    = 128;

// (1/sqrt(HD)) * log2(e): folded into Q at projection time
#define CSCALE 0.1275174475f

DEVINL unsigned cvt_pk_bf16(float lo, float hi) {
  unsigned r;
  asm("v_cvt_pk_bf16_f32 %0, %1, %2" : "=v"(r) : "v"(lo), "v"(hi));
  return r;
}

DEVINL void permswap32(unsigned &a, unsigned &b) {
  asm("v_permlane32_swap_b32 %0, %1" : "+v"(a), "+v"(b));
}

DEVINL short8 mk_frag(unsigned w0, unsigned w1, unsigned w2, unsigned w3) {
  union { unsigned u[4]; short8 s; } t;
  t.u[0] = w0; t.u[1] = w1; t.u[2] = w2; t.u[3] = w3;
  return t.s;
}

// async global->LDS, 16B per lane; LDS dest = uniform base + lane*16
DEVINL void gload16(const void* g, void* l) {
  __builtin_amdgcn_global_load_lds(
      (const __attribute__((address_space(1))) void*)g,
      (__attribute__((address_space(3))) void*)l, 16, 0, 0);
}

// ---------------------------------------------------------------------------
// Kernel 0: convert the three weight matrices to bf16 once.
// ---------------------------------------------------------------------------
__global__ __launch_bounds__(256) void wconv_kernel(
    const float* __restrict__ Wq, const float* __restrict__ Wk,
    const float* __restrict__ Wv, __hip_bfloat16* __restrict__ Wb)
{
  const int i = blockIdx.x * 256 + threadIdx.x;
  const int which = i >> 13;
  const int off = (i & 8191) << 2;
  const float* W = which == 0 ? Wq : which == 1 ? Wk : Wv;
  float4 f = *(const float4*)(W + off);
  unsigned lo = cvt_pk_bf16(f.x, f.y), hi = cvt_pk_bf16(f.z, f.w);
  unsigned long long pk = ((unsigned long long)hi << 32) | (unsigned long long)lo;
  *(unsigned long long*)(Wb + (size_t)which * 32768 + off) = pk;
}

// ---------------------------------------------------------------------------
// Kernel 1: one-pass QKV projection.
// Q row-major (pre-scaled by CSCALE). K stored with 256B-row XOR pre-swizzle:
//   physical byte = row*256 + ((2h) ^ ((row&15)<<4)).
// V stored transposed Vt[b][h][s], pre-swizzled within each 256B window:
//   byte = h*8192 + (c & ~255) + ((c & 255) ^ ((h&15)<<4)),  c = 2*s.
// ---------------------------------------------------------------------------
__global__ __launch_bounds__(256) void qkv_proj_kernel(
    const float* __restrict__ X, const __hip_bfloat16* __restrict__ Wb,
    const float* __restrict__ bq, const float* __restrict__ bk,
    const float* __restrict__ bv,
    __hip_bfloat16* __restrict__ Qw, __hip_bfloat16* __restrict__ Kw,
    __hip_bfloat16* __restrict__ Vt)
{
  alignas(16) __shared__ char sT[128 * 128];

  const int m0   = blockIdx.x * 64;
  const int tid  = threadIdx.x;
  const int wid  = tid >> 6;
  const int lane = tid & 63;
  const int wr   = wid >> 1, wc = wid & 1;
  const int l15  = lane & 15, l4 = lane >> 4;

  f32x4 acc[3][2][4];
#pragma unroll
  for (int w = 0; w < 3; ++w)
#pragma unroll
    for (int qt = 0; qt < 2; ++qt)
#pragma unroll
      for (int nt = 0; nt < 4; ++nt)
#pragma unroll
        for (int r = 0; r < 4; ++r) acc[w][qt][nt][r] = 0.f;

  const int arow = m0 + wr * 32 + l15;
  const int hrow = wc * 64 + l15;

#pragma unroll
  for (int es = 0; es < 8; ++es) {
    const int k0 = es * 32 + l4 * 8;
    short8 af[2];
#pragma unroll
    for (int qt = 0; qt < 2; ++qt) {
      const float* src = X + (size_t)(arow + qt * 16) * EMB + k0;
      float4 f0 = *(const float4*)(src);
      float4 f1 = *(const float4*)(src + 4);
      af[qt] = mk_frag(cvt_pk_bf16(f0.x, f0.y), cvt_pk_bf16(f0.z, f0.w),
                       cvt_pk_bf16(f1.x, f1.y), cvt_pk_bf16(f1.z, f1.w));
    }
#pragma unroll
    for (int w = 0; w < 3; ++w) {
      short8 bf[4];
#pragma unroll
      for (int nt = 0; nt < 4; ++nt)
        bf[nt] = *(const short8*)(Wb + (size_t)w * 32768 +
                                  (size_t)(hrow + nt * 16) * EMB + k0);
#pragma unroll
      for (int qt = 0; qt < 2; ++qt)
#pragma unroll
        for (int nt = 0; nt < 4; ++nt)
          acc[w][qt][nt] = __builtin_amdgcn_mfma_f32_16x16x32_bf16(
              af[qt], bf[nt], acc[w][qt][nt], 0, 0, 0);
    }
  }

  // --- Q (scaled, linear) and K (pre-swizzled rows) ---
#pragma unroll
  for (int qt = 0; qt < 2; ++qt)
#pragma unroll
    for (int nt = 0; nt < 4; ++nt) {
      const int h = wc * 64 + nt * 16 + l15;
      const float bbq = bq[h], bbk = bk[h];
      const int srow = m0 + wr * 32 + qt * 16 + l4 * 4;
#pragma unroll
      for (int r = 0; r < 4; ++r) {
        const int row = srow + r;
        Qw[(size_t)row * HD + h] =
            __float2bfloat16((acc[0][qt][nt][r] + bbq) * CSCALE);
        *(__hip_bfloat16*)((char*)Kw + (size_t)row * 256 +
                           (((unsigned)(h * 2)) ^ (unsigned)((row & 15) << 4))) =
            __float2bfloat16(acc[1][qt][nt][r] + bbk);
      }
    }

  // --- V: stage transposed [h][s] in LDS (local swizzle), then 16B stores ---
#pragma unroll
  for (int qt = 0; qt < 2; ++qt)
#pragma unroll
    for (int nt = 0; nt < 4; ++nt) {
      const int h = wc * 64 + nt * 16 + l15;
      const float bb = bv[h];
      const int s_rel = wr * 32 + qt * 16 + l4 * 4;
      unsigned w0 = cvt_pk_bf16(acc[2][qt][nt][0] + bb, acc[2][qt][nt][1] + bb);
      unsigned w1 = cvt_pk_bf16(acc[2][qt][nt][2] + bb, acc[2][qt][nt][3] + bb);
      unsigned long long pk = ((unsigned long long)w1 << 32) | (unsigned long long)w0;
      *(unsigned long long*)(sT + h * 128 + ((s_rel * 2) ^ ((h & 7) << 4))) = pk;
    }
  __syncthreads();
  const int bi = m0 >> 12;
  const int s_base = m0 & (SEQ - 1);
  char* Vb = (char*)Vt + (size_t)bi * HD * SEQ * 2;
#pragma unroll
  for (int p = 0; p < 4; ++p) {
    const int idx = p * 256 + tid;
    const int h = idx >> 3, slot = idx & 7;
    short8 v = *(const short8*)(sT + h * 128 + ((slot * 16) ^ ((h & 7) << 4)));
    const unsigned c = (unsigned)(s_base * 2) + (unsigned)slot * 16;
    const unsigned cw = (c & ~255u) + ((c & 255u) ^ (unsigned)((h & 15) << 4));
    *(short8*)(Vb + (size_t)h * (SEQ * 2) + cw) = v;
  }
}

// per-qt online softmax + P->bf16 B-frags (proven R2 math, kv-chunk of 32)
#define SOFTMAX_PB(SV, MV, LV, OA, PB)                                        \
  {                                                                           \
    float cmax = -1e30f;                                                      \
    _Pragma("unroll") for (int r = 0; r < 16; ++r) cmax = fmaxf(cmax, SV[r]); \
    cmax = fmaxf(cmax, __shfl_xor(cmax, 32, 64));                             \
    if (!__all(cmax - MV <= 8.0f)) {                                          \
      const float newm = fmaxf(MV, cmax);                                     \
      const float sc = __builtin_amdgcn_exp2f(MV - newm);                     \
      _Pragma("unroll") for (int dt = 0; dt < 4; ++dt)                        \
        _Pragma("unroll") for (int r = 0; r < 16; ++r) OA[dt][r] *= sc;       \
      LV *= sc;                                                               \
      MV = newm;                                                              \
    }                                                                         \
    float ls = 0.f;                                                           \
    _Pragma("unroll") for (int r = 0; r < 16; ++r) {                          \
      SV[r] = __builtin_amdgcn_exp2f(SV[r] - MV);                             \
      ls += SV[r];                                                            \
    }                                                                         \
    LV += ls;                                                                 \
    _Pragma("unroll") for (int h2 = 0; h2 < 2; ++h2) {                        \
      unsigned a0 = cvt_pk_bf16(SV[8 * h2 + 0], SV[8 * h2 + 1]);              \
      unsigned a1 = cvt_pk_bf16(SV[8 * h2 + 2], SV[8 * h2 + 3]);              \
      unsigned b0 = cvt_pk_bf16(SV[8 * h2 + 4], SV[8 * h2 + 5]);              \
      unsigned b1 = cvt_pk_bf16(SV[8 * h2 + 6], SV[8 * h2 + 7]);              \
      permswap32(a0, b0);                                                     \
      permswap32(a1, b1);                                                     \
      PB[h2] = mk_frag(a0, a1, b0, b1);                                       \
    }                                                                         \
  }

// ---------------------------------------------------------------------------
// Kernel 2: flash attention. 8 waves = 2 q-groups x 4 kv-streams; q=64/wave.
// Joint 128-kv tile per iter: K [128][256B] + V^T [128][256B], both XOR-
// swizzled, staged direct via global_load_lds (pre-swizzled global layout).
// Double-buffered, 1 barrier/iter. 4-way flash merge at the end.
// ---------------------------------------------------------------------------
__global__ __launch_bounds__(512, 2) void fused_attn_kernel(
    const __hip_bfloat16* __restrict__ Qw,
    const __hip_bfloat16* __restrict__ Kw,
    const __hip_bfloat16* __restrict__ Vt,
    float* __restrict__ out)
{
  // 0..64K: buf0 (K 32KB | V 32KB); 64K..128K: buf1; 128K..132K: stats
  alignas(16) __shared__ char smem[135168];
  float* sStat = (float*)(smem + 131072);   // [8 wid][2 qt][{m,l}][32]

  const int tid  = threadIdx.x;
  const int wid  = tid >> 6;
  const int lane = tid & 63;
  const int l31  = lane & 31;
  const int hi   = lane >> 5;
  const int strm = wid & 3;
  const int qg   = wid >> 2;

  const int b  = blockIdx.x & 7;           // batch on low bits -> XCD-local K/V
  const int q0 = (blockIdx.x >> 3) * 128;

  const char* Kg = (const char*)Kw + (size_t)b * SEQ * 256;
  const char* Vg = (const char*)Vt + (size_t)b * HD * SEQ * 2;

  // Q B-frags: q = q0 + qg*64 + qt*32 + l31, k = es*16 + hi*8
  const __hip_bfloat16* Qp = Qw + ((size_t)b * SEQ + q0 + qg * 64 + l31) * HD;
  short8 qf0[8], qf1[8];
#pragma unroll
  for (int es = 0; es < 8; ++es) {
    qf0[es] = *(const short8*)(Qp + es * 16 + hi * 8);
    qf1[es] = *(const short8*)(Qp + 32 * HD + es * 16 + hi * 8);
  }

  f32x16 oacc0[4], oacc1[4];
#pragma unroll
  for (int dt = 0; dt < 4; ++dt)
#pragma unroll
    for (int r = 0; r < 16; ++r) { oacc0[dt][r] = 0.f; oacc1[dt][r] = 0.f; }

  float m0v = -1e30f, m1v = -1e30f, l0v = 0.f, l1v = 0.f;

  // staging: waves 0-3 stage K (8KB each), waves 4-7 stage V^T (8KB each)
  const size_t vlaneoff = (size_t)(lane >> 4) * (SEQ * 2) + (size_t)(lane & 15) * 16;

  auto stage = [&](int t, int bufbase) {
    if (wid < 4) {
      const char* gb = Kg + (size_t)t * (128 * 256) + (size_t)wid * 8192 +
                       (size_t)lane * 16;
      char* lb = smem + bufbase + wid * 8192;
#pragma unroll
      for (int p = 0; p < 8; ++p)
        gload16(gb + p * 1024, lb + p * 1024);
    } else {
      const char* gb = Vg + (size_t)(wid - 4) * 32 * (SEQ * 2) +
                       (size_t)t * 256 + vlaneoff;
      char* lb = smem + bufbase + 32768 + (wid - 4) * 8192;
#pragma unroll
      for (int p = 0; p < 8; ++p)
        gload16(gb + (size_t)p * 4 * (SEQ * 2), lb + p * 1024);
    }
  };

  const int kr = strm * 32 + l31;                       // K LDS row
  const unsigned kkey = (unsigned)((kr & 15) << 4);

  stage(0, 0);                                          // prologue

  const int NT = SEQ / 128;                             // 32 iters
  for (int t = 0; t < NT; ++t) {
    const int B = (t & 1) * 65536;
    asm volatile("s_waitcnt vmcnt(0)" ::: "memory");    // own tile-t loads done
    __builtin_amdgcn_s_barrier();                       // all waves: tile ready
    __builtin_amdgcn_sched_barrier(0);
    if (t + 1 < NT) stage(t + 1, B ^ 65536);            // flies under compute

    const char* sK = smem + B;
    const char* sV = smem + B + 32768;

    // ---- QK: shared A-reads feed both q-tiles ----
    f32x16 s0, s1;
#pragma unroll
    for (int r = 0; r < 16; ++r) { s0[r] = 0.f; s1[r] = 0.f; }
    __builtin_amdgcn_s_setprio(1);
#pragma unroll
    for (int es = 0; es < 8; ++es) {
      short8 ka = *(const short8*)(sK + kr * 256 + ((es * 32 + hi * 16) ^ kkey));
      s0 = __builtin_amdgcn_mfma_f32_32x32x16_bf16(ka, qf0[es], s0, 0, 0, 0);
      s1 = __builtin_amdgcn_mfma_f32_32x32x16_bf16(ka, qf1[es], s1, 0, 0, 0);
    }
    __builtin_amdgcn_s_setprio(0);

    short8 pb0[2], pb1[2];
    SOFTMAX_PB(s0, m0v, l0v, oacc0, pb0);
    SOFTMAX_PB(s1, m1v, l1v, oacc1, pb1);

    // ---- PV: shared V A-reads feed both q-tiles ----
    __builtin_amdgcn_s_setprio(1);
#pragma unroll
    for (int ks = 0; ks < 2; ++ks)
#pragma unroll
      for (int dt = 0; dt < 4; ++dt) {
        const int vr = dt * 32 + l31;
        const unsigned vkey = (unsigned)((vr & 15) << 4);
        short8 va = *(const short8*)(sV + vr * 256 +
                                     ((strm * 64 + ks * 32 + hi * 16) ^ vkey));
        oacc0[dt] = __builtin_amdgcn_mfma_f32_32x32x16_bf16(va, pb0[ks], oacc0[dt], 0, 0, 0);
        oacc1[dt] = __builtin_amdgcn_mfma_f32_32x32x16_bf16(va, pb1[ks], oacc1[dt], 0, 0, 0);
      }
    __builtin_amdgcn_s_setprio(0);
  }

  // ---- 4-way flash merge across kv-streams (same qg) ----
  const float lt0 = l0v + __shfl_xor(l0v, 32, 64);
  const float lt1 = l1v + __shfl_xor(l1v, 32, 64);
  if (hi == 0) {
    sStat[wid * 128 + 0 + l31]       = m0v;
    sStat[wid * 128 + 32 + l31]      = lt0;
    sStat[wid * 128 + 64 + l31]      = m1v;
    sStat[wid * 128 + 96 + l31]      = lt1;
  }
  __syncthreads();

  float M0 = -1e30f, M1 = -1e30f;
#pragma unroll
  for (int s = 0; s < 4; ++s) {
    M0 = fmaxf(M0, sStat[(qg * 4 + s) * 128 + l31]);
    M1 = fmaxf(M1, sStat[(qg * 4 + s) * 128 + 64 + l31]);
  }
  float Lt0 = 0.f, Lt1 = 0.f;
#pragma unroll
  for (int s = 0; s < 4; ++s) {
    Lt0 += sStat[(qg * 4 + s) * 128 + 32 + l31] *
           __builtin_amdgcn_exp2f(sStat[(qg * 4 + s) * 128 + l31] - M0);
    Lt1 += sStat[(qg * 4 + s) * 128 + 96 + l31] *
           __builtin_amdgcn_exp2f(sStat[(qg * 4 + s) * 128 + 64 + l31] - M1);
  }
  const float a0 = __builtin_amdgcn_exp2f(m0v - M0);
  const float a1 = __builtin_amdgcn_exp2f(m1v - M1);

  float* reg = (float*)(smem + qg * 32768);   // [128 d][64 q] f32
  for (int s = 0; s < 4; ++s) {
    if (strm == s) {
#pragma unroll
      for (int dt = 0; dt < 4; ++dt)
#pragma unroll
        for (int r = 0; r < 16; ++r) {
          const int d = dt * 32 + (r & 3) + 8 * (r >> 2) + 4 * hi;
          float* p0 = reg + d * 64 + l31;
          float* p1 = reg + d * 64 + 32 + l31;
          if (s == 0) {
            *p0 = oacc0[dt][r] * a0;
            *p1 = oacc1[dt][r] * a1;
          } else {
            *p0 += oacc0[dt][r] * a0;
            *p1 += oacc1[dt][r] * a1;
          }
        }
    }
    __syncthreads();
  }

  // ---- output: lane = q (0..63), wave's stream owns 32 d-columns ----
  const float inv = 1.0f / (hi ? Lt1 : Lt0);
  float* op = out + ((size_t)b * SEQ + q0 + qg * 64 + lane) * HD + strm * 32;
#pragma unroll
  for (int dd = 0; dd < 32; dd += 4) {
    const int d = strm * 32 + dd;
    float4 v;
    v.x = reg[(d + 0) * 64 + lane] * inv;
    v.y = reg[(d + 1) * 64 + lane] * inv;
    v.z = reg[(d + 2) * 64 + lane] * inv;
    v.w = reg[(d + 3) * 64 + lane] * inv;
    *(float4*)(op + dd) = v;
  }
}

// ---------------------------------------------------------------------------
extern "C" void kernel_launch(void* const* d_in, const int* in_sizes, int n_in,
                              void* d_out, int out_size, void* d_ws, size_t ws_size,
                              hipStream_t stream) {
  (void)in_sizes; (void)n_in; (void)out_size; (void)ws_size;
  const float* X  = (const float*)d_in[0];
  const float* Wk = (const float*)d_in[1];
  const float* bk = (const float*)d_in[2];
  const float* Wq = (const float*)d_in[3];
  const float* bq = (const float*)d_in[4];
  const float* Wv = (const float*)d_in[5];
  const float* bv = (const float*)d_in[6];
  float* out = (float*)d_out;

  __hip_bfloat16* Qw = (__hip_bfloat16*)d_ws;
  __hip_bfloat16* Kw = Qw + (size_t)BATCH * SEQ * HD;
  __hip_bfloat16* Vt = Kw + (size_t)BATCH * SEQ * HD;
  __hip_bfloat16* Wb = Vt + (size_t)BATCH * SEQ * HD;

  wconv_kernel<<<96, 256, 0, stream>>>(Wq, Wk, Wv, Wb);
  qkv_proj_kernel<<<BATCH * SEQ / 64, 256, 0, stream>>>(
      X, Wb, bq, bk, bv, Qw, Kw, Vt);
  fused_attn_kernel<<<BATCH * (SEQ / 128), 512, 0, stream>>>(Qw, Kw, Vt, out);
}